// Round 12
// baseline (272.550 us; speedup 1.0000x reference)
//
#include <hip/hip_runtime.h>
#include <hip/hip_bf16.h>
#include <math.h>

#define EPT 16      // edges per thread in scatter kernel
#define BCAP 16384  // bucket capacity (avg ~8.2k for uniform random, +90 sigma)

typedef _Float16 half8 __attribute__((ext_vector_type(8)));
typedef _Float16 half2v __attribute__((ext_vector_type(2)));
typedef float f32x4 __attribute__((ext_vector_type(4)));

__device__ __forceinline__ unsigned short f16r(float f) {
    _Float16 h = (_Float16)f;
    return __builtin_bit_cast(unsigned short, h);
}
__device__ __forceinline__ half2v h2(unsigned u) {
    return __builtin_bit_cast(half2v, u);
}

// ---------------- scat1 + weight pack ----------------
// blocks [0,16): pack W1/Wh/W2 into MFMA B-fragment order (fp16):
//   wp[t*1024 + hh*512 + lane*8 + j] = W[hh*32 + (lane>>4)*8 + j][t*16 + (lane&15)]
// blocks [16, 16+ebGrid): single-pass 512-node bucket binning.
//   bucket b = dst >> 9; record = (src << 9) | (dst & 511)  [needs N <= 131072]

__global__ void scat1_kernel(const int* __restrict__ src, const int* __restrict__ dst,
                             int* __restrict__ cntg, unsigned* __restrict__ ebuf, int E,
                             const float* __restrict__ W1, const float* __restrict__ Wh,
                             const float* __restrict__ W2, unsigned short* __restrict__ wp1,
                             unsigned short* __restrict__ wph, unsigned short* __restrict__ wp2) {
    if (blockIdx.x < 16) {
        int i = blockIdx.x * 256 + threadIdx.x;   // i in [0,4096)
        int j = i & 7;
        int lane = (i >> 3) & 63;
        int hh = (i >> 9) & 1;
        int t = i >> 10;
        int k = hh * 32 + (lane >> 4) * 8 + j;
        int cc = t * 16 + (lane & 15);
        wp1[i] = f16r(W1[k * 64 + cc]);
        wph[i] = f16r(Wh[k * 64 + cc]);
        if (t < 3) wp2[i] = f16r(cc < 40 ? W2[k * 40 + cc] : 0.f);
        return;
    }
    __shared__ int lh[256];
    __shared__ int lbase[256];
    int tid = threadIdx.x;
    lh[tid] = 0;
    __syncthreads();
    int base = (blockIdx.x - 16) * (256 * EPT);
    int ds[EPT], ss[EPT];
#pragma unroll
    for (int k = 0; k < EPT; ++k) {
        int e = base + k * 256 + tid;
        ds[k] = (e < E) ? dst[e] : -1;
        ss[k] = (e < E) ? src[e] : 0;
    }
#pragma unroll
    for (int k = 0; k < EPT; ++k) {
        if (ds[k] >= 0) atomicAdd(&lh[ds[k] >> 9], 1);
    }
    __syncthreads();
    if (lh[tid] > 0) lbase[tid] = atomicAdd(&cntg[tid], lh[tid]);
    lh[tid] = 0;
    __syncthreads();
#pragma unroll
    for (int k = 0; k < EPT; ++k) {
        if (ds[k] >= 0) {
            int b = ds[k] >> 9;
            int pos = lbase[b] + atomicAdd(&lh[b], 1);
            ebuf[(size_t)b * BCAP + pos] = ((unsigned)ss[k] << 9) | (unsigned)(ds[k] & 511);
        }
    }
}

// ---------------- build: CSR finalize + feature convert ----------------
// one block per bucket: inline scan of bucket counts -> local degrees -> scan
// -> row_ptr/dinv -> fine scatter -> convert this bucket's 512 feature rows
// to pre-scaled fp16 (xb[row] = dinv[row]*x[row]). Block 0 zeroes the gather
// zero-row (row Npad).

__global__ void build_kernel(const unsigned* __restrict__ ebuf, const int* __restrict__ cntg,
                             int* __restrict__ row_ptr, int* __restrict__ col,
                             float* __restrict__ dinv, const float* __restrict__ x,
                             unsigned short* __restrict__ xb, int N, int E, int npadRow) {
    __shared__ int deg[512];
    __shared__ int sh[256];
    __shared__ float shd[512];
    int b = blockIdx.x;
    int tid = threadIdx.x;

    // block-local exclusive scan of the 256 bucket counts -> this bucket's start
    int v = cntg[tid];
    sh[tid] = v;
    __syncthreads();
    int val = v;
    for (int off = 1; off < 256; off <<= 1) {
        int add = 0;
        if (tid >= off) add = sh[tid - off];
        __syncthreads();
        val += add;
        sh[tid] = val;
        __syncthreads();
    }
    int start = (b > 0) ? sh[b - 1] : 0;
    int cnt = cntg[b];
    __syncthreads();

    int nodeBase = b << 9;
    int nn = N - nodeBase;
    if (nn > 512) nn = 512;
    if (nn < 0) nn = 0;
    const unsigned* eb = ebuf + (size_t)b * BCAP;

    deg[tid] = 0;
    deg[tid + 256] = 0;
    __syncthreads();
    for (int j = tid; j < cnt; j += 256) {
        atomicAdd(&deg[eb[j] & 511u], 1);
    }
    __syncthreads();

    int i0 = tid * 2, i1 = i0 + 1;
    int v0 = deg[i0], v1 = deg[i1];
    int tot = v0 + v1;
    sh[tid] = tot;
    __syncthreads();
    int val2 = tot;
    for (int off = 1; off < 256; off <<= 1) {
        int add = 0;
        if (tid >= off) add = sh[tid - off];
        __syncthreads();
        val2 += add;
        sh[tid] = val2;
        __syncthreads();
    }
    int excl = val2 - tot;

    float d0 = rsqrtf((float)v0 + 1.0f);
    float d1 = rsqrtf((float)v1 + 1.0f);
    shd[i0] = d0;
    shd[i1] = d1;
    if (i0 < nn) { row_ptr[nodeBase + i0] = start + excl;      dinv[nodeBase + i0] = d0; }
    if (i1 < nn) { row_ptr[nodeBase + i1] = start + excl + v0; dinv[nodeBase + i1] = d1; }
    if (b == 0 && tid == 0) row_ptr[N] = E;
    // repurpose deg[] as absolute write cursors
    deg[i0] = start + excl;
    deg[i1] = start + excl + v0;
    __syncthreads();

    for (int j = tid; j < cnt; j += 256) {
        unsigned rec = eb[j];
        int pos = atomicAdd(&deg[rec & 511u], 1);
        col[pos] = (int)(rec >> 9);
    }

    // feature convert for this bucket's nodes (dinv known locally in shd)
    int n4 = nn * 16;   // float4 groups
    for (int j = tid; j < n4; j += 256) {
        int r = j >> 4;
        float dn = shd[r];
        float4 vx = ((const float4*)x)[(size_t)(nodeBase + r) * 16 + (j & 15)];
        ushort4 o;
        o.x = f16r(vx.x * dn); o.y = f16r(vx.y * dn);
        o.z = f16r(vx.z * dn); o.w = f16r(vx.w * dn);
        *(ushort4*)(xb + (size_t)(nodeBase + r) * 64 + (j & 15) * 4) = o;
    }
    if (b == 0 && tid < 8) {
        *(uint4*)(xb + (size_t)npadRow * 64 + tid * 8) = make_uint4(0, 0, 0, 0);
    }
}

// ---------------- aggregation: agg[node] = di * sum_{j in N(i)+self} h'[j] ----
// h' is producer-pre-scaled (h'[j] = dj*h[j]): pure unweighted packed-f16 sum.
// One wave per node. Inner loop issues 4 row-loads covering 32 edge slots per
// iteration (4KB in flight/wave — Little's law needs the depth); tail slots
// are branchless via the zero row (vi >= total -> idx = zrow, hot L1 lines).

__launch_bounds__(256, 8)
__global__ void agg_kernel(const unsigned short* __restrict__ h, const int* __restrict__ row_ptr,
                           const int* __restrict__ col, const float* __restrict__ dinv,
                           unsigned short* __restrict__ aggout, int n, int zrow) {
    int tid = threadIdx.x;
    int lane = tid & 63;
    int node = blockIdx.x * 4 + (tid >> 6);
    if (node >= n) return;

    int sub = lane >> 3;                 // edge slot 0..7
    unsigned choff = (lane & 7) * 16u;   // byte offset of channel-oct in 128B row

    int beg = row_ptr[node];
    int deg = row_ptr[node + 1] - beg;
    float di = dinv[node];
    int total = deg + 1;                 // + self edge

    half2v a0 = (half2v)0, a1 = (half2v)0, a2 = (half2v)0, a3 = (half2v)0;

    int base = 0;
    while (base < total) {
        int vi = base + lane;
        int idx = zrow;                  // tail -> zero row (branchless loads)
        if (vi < deg) idx = col[beg + vi];
        else if (vi == deg) idx = node;  // self edge (h'[node] = dn*h[node])
        int cnt = min(total - base, 64);
#pragma unroll
        for (int half = 0; half < 2; ++half) {
            int c0 = half * 32;
            if (c0 >= cnt) break;        // wave-uniform
            int s0 = __shfl(idx, c0 + sub);
            int s1 = __shfl(idx, c0 + 8 + sub);
            int s2 = __shfl(idx, c0 + 16 + sub);
            int s3 = __shfl(idx, c0 + 24 + sub);
            uint4 u0 = *(const uint4*)((const char*)h + (((unsigned)s0 << 7) + choff));
            uint4 u1 = *(const uint4*)((const char*)h + (((unsigned)s1 << 7) + choff));
            uint4 u2 = *(const uint4*)((const char*)h + (((unsigned)s2 << 7) + choff));
            uint4 u3 = *(const uint4*)((const char*)h + (((unsigned)s3 << 7) + choff));
            a0 += h2(u0.x);  a1 += h2(u0.y);  a2 += h2(u0.z);  a3 += h2(u0.w);
            a0 += h2(u1.x);  a1 += h2(u1.y);  a2 += h2(u1.z);  a3 += h2(u1.w);
            a0 += h2(u2.x);  a1 += h2(u2.y);  a2 += h2(u2.z);  a3 += h2(u2.w);
            a0 += h2(u3.x);  a1 += h2(u3.y);  a2 += h2(u3.z);  a3 += h2(u3.w);
        }
        base += cnt;
    }
    // reduce the 8 edge slots (lane bits 3,4,5) in packed f16
#pragma unroll
    for (int off = 8; off <= 32; off <<= 1) {
        a0 += __builtin_bit_cast(half2v, __shfl_xor(__builtin_bit_cast(int, a0), off));
        a1 += __builtin_bit_cast(half2v, __shfl_xor(__builtin_bit_cast(int, a1), off));
        a2 += __builtin_bit_cast(half2v, __shfl_xor(__builtin_bit_cast(int, a2), off));
        a3 += __builtin_bit_cast(half2v, __shfl_xor(__builtin_bit_cast(int, a3), off));
    }

    if (sub == 0) {
        half2v dih = __builtin_bit_cast(half2v, __builtin_amdgcn_cvt_pkrtz(di, di));
        a0 *= dih; a1 *= dih; a2 *= dih; a3 *= dih;   // v_pk_mul_f16
        uint4 o;
        o.x = __builtin_bit_cast(unsigned, a0);
        o.y = __builtin_bit_cast(unsigned, a1);
        o.z = __builtin_bit_cast(unsigned, a2);
        o.w = __builtin_bit_cast(unsigned, a3);
        *(uint4*)((char*)aggout + (((unsigned)node << 7) + choff)) = o;
    }
}

// ---------------- MFMA epilogue GEMMs (f16) ----------------
// gemm_relu stores the NEXT layer's pre-scaled features:
//   out[node] = dinv[node] * relu(A@W + b), and zeroes the gather zero-row.

__global__ void gemm_relu_kernel(const unsigned short* __restrict__ A,
                                 const unsigned short* __restrict__ wp,
                                 const float* __restrict__ bias,
                                 const float* __restrict__ dinv,
                                 unsigned short* __restrict__ out, int nTiles, int n, int zrow) {
    if (blockIdx.x == 0 && threadIdx.x < 8) {
        *(uint4*)(out + (size_t)zrow * 64 + threadIdx.x * 8) = make_uint4(0, 0, 0, 0);
    }
    int wv = blockIdx.x * 4 + (threadIdx.x >> 6);
    int lane = threadIdx.x & 63;
    if (wv >= nTiles) return;
    int q = lane >> 4, c = lane & 15;

    half8 bfrag[4][2];
#pragma unroll
    for (int t = 0; t < 4; ++t)
#pragma unroll
        for (int hh = 0; hh < 2; ++hh)
            bfrag[t][hh] = *(const half8*)(wp + t * 1024 + hh * 512 + lane * 8);
    float bs[4];
#pragma unroll
    for (int t = 0; t < 4; ++t) bs[t] = bias[t * 16 + c];

    int nodeBase = wv * 16;
    const unsigned short* arow = A + (size_t)(nodeBase + c) * 64 + q * 8;
    half8 a0 = *(const half8*)(arow);
    half8 a1 = *(const half8*)(arow + 32);

    f32x4 acc[4];
#pragma unroll
    for (int t = 0; t < 4; ++t) {
        f32x4 z = {0.f, 0.f, 0.f, 0.f};
        z = __builtin_amdgcn_mfma_f32_16x16x32_f16(a0, bfrag[t][0], z, 0, 0, 0);
        z = __builtin_amdgcn_mfma_f32_16x16x32_f16(a1, bfrag[t][1], z, 0, 0, 0);
        acc[t] = z;
    }

#pragma unroll
    for (int r = 0; r < 4; ++r) {
        int node = nodeBase + q * 4 + r;
        if (node < n) {
            float dn = dinv[node];
            unsigned short* orow = out + (size_t)node * 64;
#pragma unroll
            for (int t = 0; t < 4; ++t)
                orow[t * 16 + c] = f16r(fmaxf(acc[t][r] + bs[t], 0.f) * dn);
        }
    }
}

__global__ void gemm_lsm_kernel(const unsigned short* __restrict__ A,
                                const unsigned short* __restrict__ wp,
                                const float* __restrict__ bias,
                                float* __restrict__ out, int nTiles, int n) {
    int wv = blockIdx.x * 4 + (threadIdx.x >> 6);
    int lane = threadIdx.x & 63;
    if (wv >= nTiles) return;
    int q = lane >> 4, c = lane & 15;
    bool v2ok = (c < 8);   // col 32+c < 40

    half8 bfrag[3][2];
#pragma unroll
    for (int t = 0; t < 3; ++t)
#pragma unroll
        for (int hh = 0; hh < 2; ++hh)
            bfrag[t][hh] = *(const half8*)(wp + t * 1024 + hh * 512 + lane * 8);
    float bs[3];
    bs[0] = bias[c];
    bs[1] = bias[16 + c];
    bs[2] = v2ok ? bias[32 + c] : 0.f;

    int nodeBase = wv * 16;
    const unsigned short* arow = A + (size_t)(nodeBase + c) * 64 + q * 8;
    half8 a0 = *(const half8*)(arow);
    half8 a1 = *(const half8*)(arow + 32);

    f32x4 acc[3];
#pragma unroll
    for (int t = 0; t < 3; ++t) {
        f32x4 z = {0.f, 0.f, 0.f, 0.f};
        z = __builtin_amdgcn_mfma_f32_16x16x32_f16(a0, bfrag[t][0], z, 0, 0, 0);
        z = __builtin_amdgcn_mfma_f32_16x16x32_f16(a1, bfrag[t][1], z, 0, 0, 0);
        acc[t] = z;
    }

#pragma unroll
    for (int r = 0; r < 4; ++r) {
        int node = nodeBase + q * 4 + r;
        if (node < n) {
            float v0 = acc[0][r] + bs[0];
            float v1 = acc[1][r] + bs[1];
            float v2 = v2ok ? (acc[2][r] + bs[2]) : -INFINITY;
            float m = fmaxf(fmaxf(v0, v1), v2);
#pragma unroll
            for (int off = 1; off <= 8; off <<= 1) m = fmaxf(m, __shfl_xor(m, off));
            float s = expf(v0 - m) + expf(v1 - m) + (v2ok ? expf(v2 - m) : 0.f);
#pragma unroll
            for (int off = 1; off <= 8; off <<= 1) s += __shfl_xor(s, off);
            float ls = m + logf(s);
            float* orow = out + (size_t)node * 40;
            orow[c] = v0 - ls;
            orow[16 + c] = v1 - ls;
            if (v2ok) orow[32 + c] = v2 - ls;
        }
    }
}

// ---------------- launch ----------------

extern "C" void kernel_launch(void* const* d_in, const int* in_sizes, int n_in,
                              void* d_out, int out_size, void* d_ws, size_t ws_size,
                              hipStream_t stream) {
    const float* x  = (const float*)d_in[0];
    const int* ei   = (const int*)d_in[1];
    const float* W1 = (const float*)d_in[2];
    const float* b1 = (const float*)d_in[3];
    const float* Wh = (const float*)d_in[4];
    const float* bh = (const float*)d_in[5];
    const float* W2 = (const float*)d_in[6];
    const float* b2 = (const float*)d_in[7];
    float* out = (float*)d_out;

    const int N = in_sizes[0] / 64;
    const int E = in_sizes[1] / 2;
    const int nbuk = (N + 511) >> 9;         // 512-node buckets (needs N <= 131072)
    const int nTiles = (N + 15) / 16;
    const int Npad = nTiles * 16;            // zero-row index; buffers have Npad+1 rows

    const int* srcp = ei;
    const int* dstp = ei + E;

    size_t off = 0;
    auto alloc = [&](size_t bytes) {
        size_t o = off;
        off = (off + bytes + 255) & ~(size_t)255;
        return o;
    };
    char* ws = (char*)d_ws;
    int*      cntg    = (int*)(ws + alloc(256 * 4));
    int*      row_ptr = (int*)(ws + alloc((size_t)(N + 1) * 4));
    float*    dinv    = (float*)(ws + alloc((size_t)N * 4));
    int*      col     = (int*)(ws + alloc((size_t)E * 4));
    unsigned* ebuf    = (unsigned*)(ws + alloc((size_t)nbuk * BCAP * 4));
    unsigned short* wp1  = (unsigned short*)(ws + alloc(4096 * 2));
    unsigned short* wph  = (unsigned short*)(ws + alloc(4096 * 2));
    unsigned short* wp2  = (unsigned short*)(ws + alloc(3072 * 2));
    unsigned short* xb   = (unsigned short*)(ws + alloc((size_t)(Npad + 1) * 64 * 2));
    unsigned short* aggA = (unsigned short*)(ws + alloc((size_t)Npad * 64 * 2));
    unsigned short* gA   = (unsigned short*)(ws + alloc((size_t)(Npad + 1) * 64 * 2));
    (void)ws_size;

    hipMemsetAsync(cntg, 0, 256 * 4, stream);

    const int ebGrid = (E + 256 * EPT - 1) / (256 * EPT);
    scat1_kernel<<<16 + ebGrid, 256, 0, stream>>>(srcp, dstp, cntg, ebuf, E,
                                                  W1, Wh, W2, wp1, wph, wp2);
    build_kernel<<<nbuk, 256, 0, stream>>>(ebuf, cntg, row_ptr, col, dinv, x, xb, N, E, Npad);

    const int aggGrid = (N + 3) / 4;
    const int gemmGrid = (nTiles + 3) / 4;

    // layer 1
    agg_kernel<<<aggGrid, 256, 0, stream>>>(xb, row_ptr, col, dinv, aggA, N, Npad);
    gemm_relu_kernel<<<gemmGrid, 256, 0, stream>>>(aggA, wp1, b1, dinv, gA, nTiles, N, Npad);
    // layer 2
    agg_kernel<<<aggGrid, 256, 0, stream>>>(gA, row_ptr, col, dinv, aggA, N, Npad);
    gemm_relu_kernel<<<gemmGrid, 256, 0, stream>>>(aggA, wph, bh, dinv, gA, nTiles, N, Npad);
    // layer 3
    agg_kernel<<<aggGrid, 256, 0, stream>>>(gA, row_ptr, col, dinv, aggA, N, Npad);
    gemm_lsm_kernel<<<gemmGrid, 256, 0, stream>>>(aggA, wp2, b2, out, nTiles, N);
}